// Round 1
// baseline (204.066 us; speedup 1.0000x reference)
//
#include <hip/hip_runtime.h>
#include <hip/hip_bf16.h>

typedef __bf16 bf16x8 __attribute__((ext_vector_type(8)));
typedef __bf16 bf16x4 __attribute__((ext_vector_type(4)));
typedef float  f32x4  __attribute__((ext_vector_type(4)));

#define HL   50     // history length
#define DD   64     // embed dim
#define NPB  4      // nodes per block
#define XSS  136    // xs row stride in bf16 (128 + 8 pad -> 2-way bank alias, free)
#define H1S  72     // h1s row stride in bf16 (64 + 8 pad)

// Fused: gather -> [eva|eaf] @ W1(+rep-folded bias) -> relu -> @W2 -> relu -> .w3
//        -> softmax over L -> weighted sum of e_va (f32 path for output precision)
__global__ __launch_bounds__(256, 4) void va_agg_kernel(
    const int*   __restrict__ nodes,
    const int*   __restrict__ hva,
    const int*   __restrict__ haf,
    const float* __restrict__ v2e,
    const float* __restrict__ a2e,
    const float* __restrict__ f2e,
    const float* __restrict__ W1,
    const float* __restrict__ b1,
    const float* __restrict__ W2,
    const float* __restrict__ b2,
    const float* __restrict__ w3,
    float*       __restrict__ out)
{
    __shared__ __bf16 xs[64 * XSS];     // [row 0..63][k 0..127] : e_va | e_af (bf16)
    __shared__ __bf16 h1s[64 * H1S];    // relu(h1) for GEMM2 A-operand
    __shared__ float  eva32[HL * DD];   // f32 e_va for the output weighted sum
    __shared__ float  repbuf[DD];       // f32 rep = v2e_w[nodes[n]]
    __shared__ float  pbuf[4 * 64];     // per-wave partials (scores, then out)
    __shared__ float  att_s[64];        // softmax weights

    const int tid  = threadIdx.x;
    const int w    = tid >> 6;       // wave 0..3
    const int lane = tid & 63;
    const int lq   = lane & 15;      // lane-in-16
    const int quad = lane >> 4;      // 0..3
    const int col  = w * 16 + lq;    // this lane's output column (0..63)

    // ---- B-fragments (weights) in registers, once per block ----
    // mfma_f32_16x16x32_bf16 B-layout: lane holds B[k=quad*8+j][n=lane&15]
    bf16x8 b1f[4], b2f[2];
    #pragma unroll
    for (int t = 0; t < 4; ++t) {
        #pragma unroll
        for (int j = 0; j < 8; ++j) {
            int keff = t * 32 + quad * 8 + j;          // 0..127 over [e_va|e_af]
            int krow = (keff < 64) ? keff : keff + 64; // skip W1 rows 64..127 (rep part)
            b1f[t][j] = (__bf16)W1[krow * 64 + col];
        }
    }
    #pragma unroll
    for (int t = 0; t < 2; ++t)
        #pragma unroll
        for (int j = 0; j < 8; ++j)
            b2f[t][j] = (__bf16)W2[(t * 32 + quad * 8 + j) * 64 + col];
    const float w3c = w3[col];
    const float b1c = b1[col];
    const float b2c = b2[col];

    // zero pad rows 50..63 of xs (written once; never overwritten)
    for (int i = tid; i < (64 - HL) * 32; i += 256) {
        int r = HL + i / 32;
        int c = (i % 32) * 4;
        bf16x4 z = {(__bf16)0.f, (__bf16)0.f, (__bf16)0.f, (__bf16)0.f};
        *(bf16x4*)&xs[r * XSS + c] = z;
    }

    for (int it = 0; it < NPB; ++it) {
        const int node = blockIdx.x * NPB + it;
        __syncthreads();  // protect xs/eva32/att_s from previous iteration's readers

        // ---- stage: gather e_va, e_af rows; cast bf16 into xs; keep e_va f32 ----
        {
            const int rr = tid >> 4;     // row slot within pass
            const int q  = tid & 15;     // quarter-row (4 floats each)
            #pragma unroll
            for (int base = 0; base < 112; base += 16) {
                int r = base + rr;       // 0..99 : 0..49 = e_va, 50..99 = e_af
                if (r < 2 * HL) {
                    int l = (r < HL) ? r : r - HL;
                    int idx = (r < HL) ? hva[node * HL + l] : haf[node * HL + l];
                    const float* src = ((r < HL) ? a2e : f2e) + (size_t)idx * DD + q * 4;
                    float4 v = *(const float4*)src;
                    bf16x4 pk = {(__bf16)v.x, (__bf16)v.y, (__bf16)v.z, (__bf16)v.w};
                    int cbase = (r < HL) ? q * 4 : DD + q * 4;
                    *(bf16x4*)&xs[l * XSS + cbase] = pk;
                    if (r < HL) *(float4*)&eva32[l * DD + q * 4] = v;
                }
            }
            if (tid < 16) {
                int nd = nodes[node];
                float4 v = *(const float4*)(v2e + (size_t)nd * DD + tid * 4);
                *(float4*)&repbuf[tid * 4] = v;
            }
        }
        __syncthreads();

        // ---- effective bias: b1[col] + rep . W1[64:128, col]  (f32, exact) ----
        float be = b1c;
        #pragma unroll 8
        for (int j = 0; j < 64; ++j)
            be = fmaf(repbuf[j], W1[(64 + j) * 64 + col], be);

        // ---- GEMM1: h1 = relu(x @ W1eff + be), rows 0..63, K=128 ----
        f32x4 acc[4];
        #pragma unroll
        for (int mt = 0; mt < 4; ++mt) acc[mt] = (f32x4){be, be, be, be};
        #pragma unroll
        for (int t = 0; t < 4; ++t) {
            #pragma unroll
            for (int mt = 0; mt < 4; ++mt) {
                bf16x8 a = *(const bf16x8*)&xs[(mt * 16 + lq) * XSS + t * 32 + quad * 8];
                acc[mt] = __builtin_amdgcn_mfma_f32_16x16x32_bf16(a, b1f[t], acc[mt], 0, 0, 0);
            }
        }
        // C-layout (row = mt*16 + quad*4 + r, col) -> relu -> LDS (A-layout source)
        #pragma unroll
        for (int mt = 0; mt < 4; ++mt)
            #pragma unroll
            for (int r = 0; r < 4; ++r) {
                float v = fmaxf(acc[mt][r], 0.f);
                h1s[(mt * 16 + quad * 4 + r) * H1S + col] = (__bf16)v;
            }
        __syncthreads();

        // ---- GEMM2: h2 = relu(h1 @ W2 + b2), K=64 ----
        f32x4 acc2[4];
        #pragma unroll
        for (int mt = 0; mt < 4; ++mt) acc2[mt] = (f32x4){b2c, b2c, b2c, b2c};
        #pragma unroll
        for (int t = 0; t < 2; ++t)
            #pragma unroll
            for (int mt = 0; mt < 4; ++mt) {
                bf16x8 a = *(const bf16x8*)&h1s[(mt * 16 + lq) * H1S + t * 32 + quad * 8];
                acc2[mt] = __builtin_amdgcn_mfma_f32_16x16x32_bf16(a, b2f[t], acc2[mt], 0, 0, 0);
            }

        // ---- scores: s[row] = sum_col relu(h2)*w3 ; reduce across 16 lanes ----
        #pragma unroll
        for (int mt = 0; mt < 4; ++mt) {
            float p0 = fmaxf(acc2[mt][0], 0.f) * w3c;
            float p1 = fmaxf(acc2[mt][1], 0.f) * w3c;
            float p2 = fmaxf(acc2[mt][2], 0.f) * w3c;
            float p3 = fmaxf(acc2[mt][3], 0.f) * w3c;
            #pragma unroll
            for (int m = 1; m < 16; m <<= 1) {
                p0 += __shfl_xor(p0, m);
                p1 += __shfl_xor(p1, m);
                p2 += __shfl_xor(p2, m);
                p3 += __shfl_xor(p3, m);
            }
            if (lq == 0) {
                int rowb = mt * 16 + quad * 4;
                pbuf[w * 64 + rowb + 0] = p0;
                pbuf[w * 64 + rowb + 1] = p1;
                pbuf[w * 64 + rowb + 2] = p2;
                pbuf[w * 64 + rowb + 3] = p3;
            }
        }
        __syncthreads();

        // ---- softmax over l (wave 0); +b3 omitted (softmax shift-invariant) ----
        if (w == 0) {
            float s = -3.0e38f;
            if (lane < HL)
                s = pbuf[lane] + pbuf[64 + lane] + pbuf[128 + lane] + pbuf[192 + lane];
            float mx = s;
            #pragma unroll
            for (int m = 1; m < 64; m <<= 1) mx = fmaxf(mx, __shfl_xor(mx, m));
            float e = (lane < HL) ? __expf(s - mx) : 0.f;
            float sm = e;
            #pragma unroll
            for (int m = 1; m < 64; m <<= 1) sm += __shfl_xor(sm, m);
            att_s[lane] = e / sm;
        }
        __syncthreads();

        // ---- out[n][d] = sum_l att[l] * e_va[l][d]  (f32, 4-wave split) ----
        {
            float o = 0.f;
            for (int l = w; l < HL; l += 4)
                o = fmaf(att_s[l], eva32[l * DD + lane], o);
            pbuf[w * 64 + lane] = o;
        }
        __syncthreads();
        if (w == 0) {
            float o2 = pbuf[lane] + pbuf[64 + lane] + pbuf[128 + lane] + pbuf[192 + lane];
            out[(size_t)node * DD + lane] = o2;
        }
    }
}

extern "C" void kernel_launch(void* const* d_in, const int* in_sizes, int n_in,
                              void* d_out, int out_size, void* d_ws, size_t ws_size,
                              hipStream_t stream) {
    const int*   nodes = (const int*)d_in[0];
    const int*   hva   = (const int*)d_in[1];
    const int*   haf   = (const int*)d_in[2];
    const float* v2e   = (const float*)d_in[3];
    const float* a2e   = (const float*)d_in[4];
    const float* f2e   = (const float*)d_in[5];
    const float* W1    = (const float*)d_in[6];
    const float* b1    = (const float*)d_in[7];
    const float* W2    = (const float*)d_in[8];
    const float* b2    = (const float*)d_in[9];
    const float* w3    = (const float*)d_in[10];
    // d_in[11] = b3: softmax(s + c) == softmax(s), so b3 cancels — unused.
    float* out = (float*)d_out;

    const int N = in_sizes[0];           // 8192
    const int blocks = N / NPB;          // 2048
    va_agg_kernel<<<blocks, 256, 0, stream>>>(nodes, hva, haf, v2e, a2e, f2e,
                                              W1, b1, W2, b2, w3, out);
}

// Round 2
// 173.531 us; speedup vs baseline: 1.1760x; 1.1760x over previous
//
#include <hip/hip_runtime.h>
#include <hip/hip_bf16.h>

typedef __bf16 bf16x8 __attribute__((ext_vector_type(8)));
typedef __bf16 bf16x4 __attribute__((ext_vector_type(4)));
typedef float  f32x4  __attribute__((ext_vector_type(4)));

#define HL   50     // history length
#define DD   64     // embed dim
#define NPB  2      // nodes per block (batched into one phase set)
#define MR   112    // padded M rows (2*50 -> 7 tiles of 16)
#define MT   7      // M tiles
#define XSS  136    // xs row stride bf16: [e_va 0..63 | e_af/h1 64..127 | pad]
#define RSS  72     // reps row stride bf16

// One-shot batched pipeline per block (2 nodes):
//   gather -> (rep@W1mid MFMA bias) -> GEMM1(K=128) -> relu -> GEMM2 -> .w3
//   -> softmax -> weighted sum of e_va (read back from xs, f32 accumulate)
__global__ __launch_bounds__(256, 4) void va_agg_kernel(
    const int*   __restrict__ nodes,
    const int*   __restrict__ hva,
    const int*   __restrict__ haf,
    const float* __restrict__ v2e,
    const float* __restrict__ a2e,
    const float* __restrict__ f2e,
    const float* __restrict__ W1,
    const float* __restrict__ b1,
    const float* __restrict__ W2,
    const float* __restrict__ b2,
    const float* __restrict__ w3,
    float*       __restrict__ out)
{
    __shared__ __bf16 xs[MR * XSS];      // e_va | e_af (then h1 over e_af half)
    __shared__ __bf16 reps[16 * RSS];    // rep rows for bias MFMA (rows 2..15 zero)
    __shared__ float  rbias_s[NPB * DD]; // b1 + rep . W1[64:128]
    __shared__ float  pbuf[4 * MR];      // per-wave partials (scores, then out)
    __shared__ float  att_s[NPB * DD];   // softmax weights

    const int tid  = threadIdx.x;
    const int w    = tid >> 6;
    const int lane = tid & 63;
    const int lq   = lane & 15;
    const int quad = lane >> 4;
    const int col  = w * 16 + lq;        // this wave-lane's output column
    const int n0   = blockIdx.x * NPB;

    // ---- weight fragments in registers (L1-hot across blocks) ----
    // B-layout: lane holds B[k = quad*8 + j][n = lane&15]
    bf16x8 b1f[4], b1u[2], b2f[2];
    #pragma unroll
    for (int t = 0; t < 4; ++t)
        #pragma unroll
        for (int j = 0; j < 8; ++j) {
            int keff = t * 32 + quad * 8 + j;           // x-col 0..127
            int krow = (keff < 64) ? keff : keff + 64;  // W1 rows 0-63 / 128-191
            b1f[t][j] = (__bf16)W1[krow * 64 + col];
        }
    #pragma unroll
    for (int t = 0; t < 2; ++t)
        #pragma unroll
        for (int j = 0; j < 8; ++j) {
            b1u[t][j] = (__bf16)W1[(64 + t * 32 + quad * 8 + j) * 64 + col];
            b2f[t][j] = (__bf16)W2[(t * 32 + quad * 8 + j) * 64 + col];
        }
    const float w3c = w3[col];
    const float b1c = b1[col];
    const float b2c = b2[col];

    // ---- zero pad rows (xs 100..111, reps 2..15); stage rep rows ----
    {
        bf16x4 z = {(__bf16)0.f, (__bf16)0.f, (__bf16)0.f, (__bf16)0.f};
        for (int i = tid; i < (MR - NPB * HL) * 32; i += 256) {
            int r = NPB * HL + (i >> 5);
            int c = (i & 31) * 4;
            *(bf16x4*)&xs[r * XSS + c] = z;
        }
        for (int i = tid; i < 14 * 16; i += 256) {
            int r = 2 + (i >> 4);
            int q = i & 15;
            *(bf16x4*)&reps[r * RSS + q * 4] = z;
        }
        if (tid < NPB * 16) {
            int n = tid >> 4, q = tid & 15;
            int nd = nodes[n0 + n];
            float4 v = *(const float4*)(v2e + (size_t)nd * DD + q * 4);
            bf16x4 pk = {(__bf16)v.x, (__bf16)v.y, (__bf16)v.z, (__bf16)v.w};
            *(bf16x4*)&reps[n * RSS + q * 4] = pk;
        }
    }
    __syncthreads();

    // ---- gather 200 rows x 16 chunks (independent, latency-overlapped) ----
    {
        const int* hb = hva + n0 * HL;   // 100 contiguous indices (2 nodes)
        const int* fb = haf + n0 * HL;
        #pragma unroll
        for (int i = 0; i < 13; ++i) {
            int t = i * 256 + tid;
            if (t < NPB * HL * 2 * 16) {
                int r = t >> 4, q = t & 15;
                bool va = (r < NPB * HL);
                int gr = va ? r : r - NPB * HL;
                int idx = va ? hb[gr] : fb[gr];
                const float* src = (va ? a2e : f2e) + (size_t)idx * DD + q * 4;
                float4 v = *(const float4*)src;
                bf16x4 pk = {(__bf16)v.x, (__bf16)v.y, (__bf16)v.z, (__bf16)v.w};
                *(bf16x4*)&xs[gr * XSS + (va ? 0 : DD) + q * 4] = pk;
            }
        }
        // bias MFMA: rb[node][col] = rep . W1[64:128, col]  (reps ready since sync)
        f32x4 rb = {0.f, 0.f, 0.f, 0.f};
        #pragma unroll
        for (int t = 0; t < 2; ++t) {
            bf16x8 a = *(const bf16x8*)&reps[lq * RSS + t * 32 + quad * 8];
            rb = __builtin_amdgcn_mfma_f32_16x16x32_bf16(a, b1u[t], rb, 0, 0, 0);
        }
        if (quad == 0) {   // C rows 0,1 live in quad 0, regs 0,1
            rbias_s[0 * DD + col] = rb[0] + b1c;
            rbias_s[1 * DD + col] = rb[1] + b1c;
        }
    }
    __syncthreads();

    // ---- GEMM1: h1 = relu(x @ W1eff + rbias), M=112, K=128 ----
    f32x4 acc[MT];
    #pragma unroll
    for (int mt = 0; mt < MT; ++mt)
        #pragma unroll
        for (int r = 0; r < 4; ++r) {
            int gr = mt * 16 + quad * 4 + r;
            acc[mt][r] = rbias_s[((gr >= HL) ? 1 : 0) * DD + col];
        }
    #pragma unroll
    for (int t = 0; t < 4; ++t)
        #pragma unroll
        for (int mt = 0; mt < MT; ++mt) {
            bf16x8 a = *(const bf16x8*)&xs[(mt * 16 + lq) * XSS + t * 32 + quad * 8];
            acc[mt] = __builtin_amdgcn_mfma_f32_16x16x32_bf16(a, b1f[t], acc[mt], 0, 0, 0);
        }
    __syncthreads();   // all xs e_af reads done before overwrite
    #pragma unroll
    for (int mt = 0; mt < MT; ++mt)
        #pragma unroll
        for (int r = 0; r < 4; ++r) {
            int gr = mt * 16 + quad * 4 + r;
            xs[gr * XSS + DD + col] = (__bf16)fmaxf(acc[mt][r], 0.f);
        }
    __syncthreads();

    // ---- GEMM2 + scores ----
    f32x4 a2[MT];
    #pragma unroll
    for (int mt = 0; mt < MT; ++mt) a2[mt] = (f32x4){b2c, b2c, b2c, b2c};
    #pragma unroll
    for (int t = 0; t < 2; ++t)
        #pragma unroll
        for (int mt = 0; mt < MT; ++mt) {
            bf16x8 a = *(const bf16x8*)&xs[(mt * 16 + lq) * XSS + DD + t * 32 + quad * 8];
            a2[mt] = __builtin_amdgcn_mfma_f32_16x16x32_bf16(a, b2f[t], a2[mt], 0, 0, 0);
        }
    #pragma unroll
    for (int mt = 0; mt < MT; ++mt) {
        float p0 = fmaxf(a2[mt][0], 0.f) * w3c;
        float p1 = fmaxf(a2[mt][1], 0.f) * w3c;
        float p2 = fmaxf(a2[mt][2], 0.f) * w3c;
        float p3 = fmaxf(a2[mt][3], 0.f) * w3c;
        #pragma unroll
        for (int m = 1; m < 16; m <<= 1) {
            p0 += __shfl_xor(p0, m);
            p1 += __shfl_xor(p1, m);
            p2 += __shfl_xor(p2, m);
            p3 += __shfl_xor(p3, m);
        }
        if (lq == 0) {
            int rowb = mt * 16 + quad * 4;
            pbuf[w * MR + rowb + 0] = p0;
            pbuf[w * MR + rowb + 1] = p1;
            pbuf[w * MR + rowb + 2] = p2;
            pbuf[w * MR + rowb + 3] = p3;
        }
    }
    __syncthreads();

    // ---- softmax per node (wave w handles node w); b3 cancels ----
    if (w < NPB) {
        float s = -3.0e38f;
        if (lane < HL) {
            int gr = w * HL + lane;
            s = pbuf[gr] + pbuf[MR + gr] + pbuf[2 * MR + gr] + pbuf[3 * MR + gr];
        }
        float mx = s;
        #pragma unroll
        for (int m = 1; m < 64; m <<= 1) mx = fmaxf(mx, __shfl_xor(mx, m));
        float e = (lane < HL) ? __expf(s - mx) : 0.f;
        float sm = e;
        #pragma unroll
        for (int m = 1; m < 64; m <<= 1) sm += __shfl_xor(sm, m);
        att_s[w * DD + lane] = e / sm;
    }
    __syncthreads();

    // ---- out[n][d] = sum_l att[l] * e_va[l][d] (bf16 from xs, f32 accum) ----
    {
        int n = w & 1, lh = w >> 1;      // waves split the l-range in half
        float o0 = 0.f, o1 = 0.f;
        const int lb = lh * 25;
        #pragma unroll
        for (int i = 0; i < 25; i += 2) {
            int l = lb + i;
            o0 = fmaf(att_s[n * DD + l], (float)xs[(n * HL + l) * XSS + lane], o0);
            if (i + 1 < 25)
                o1 = fmaf(att_s[n * DD + l + 1], (float)xs[(n * HL + l + 1) * XSS + lane], o1);
        }
        pbuf[w * MR + lane] = o0 + o1;
    }
    __syncthreads();
    if (w < NPB) {
        float o = pbuf[w * MR + lane] + pbuf[(w + 2) * MR + lane];
        out[(size_t)(n0 + w) * DD + lane] = o;
    }
}

extern "C" void kernel_launch(void* const* d_in, const int* in_sizes, int n_in,
                              void* d_out, int out_size, void* d_ws, size_t ws_size,
                              hipStream_t stream) {
    const int*   nodes = (const int*)d_in[0];
    const int*   hva   = (const int*)d_in[1];
    const int*   haf   = (const int*)d_in[2];
    const float* v2e   = (const float*)d_in[3];
    const float* a2e   = (const float*)d_in[4];
    const float* f2e   = (const float*)d_in[5];
    const float* W1    = (const float*)d_in[6];
    const float* b1    = (const float*)d_in[7];
    const float* W2    = (const float*)d_in[8];
    const float* b2    = (const float*)d_in[9];
    const float* w3    = (const float*)d_in[10];
    // d_in[11] = b3: softmax shift-invariant — unused.
    float* out = (float*)d_out;

    const int N = in_sizes[0];            // 8192
    const int blocks = N / NPB;           // 4096
    va_agg_kernel<<<blocks, 256, 0, stream>>>(nodes, hva, haf, v2e, a2e, f2e,
                                              W1, b1, W2, b2, w3, out);
}